// Round 1
// 252.418 us; speedup vs baseline: 1.0080x; 1.0080x over previous
//
#include <hip/hip_runtime.h>

// Demosaic (Malvar-He-Cutler), RGGB, B=16 H=W=1024, f32 in/out. v5:
// v4 was latency/occupancy-bound: 24x float4 staging (96 VGPR) + a separate
// select-heavy v[8][8] (64 cndmask dests) peaked ~160-200 VGPRs -> ~2-3
// waves/SIMD, so the single vmcnt drain of 24 HBM loads was uncovered.
// v5 loads the EXACT 8-float window per row (float2+float4+float2 = 32B,
// was 48B), aliases loads directly into the compute window (SSA renames,
// no second array), and replaces per-element validity selects with
// block-uniform scalar-branch zeroing (only y0==0 / y0==Hn-4 blocks) plus
// 4 lane-edge cndmasks per row. Target: <=128 VGPR, >=16 waves/CU.
//
// Site map (RGGB): (0,0) R site: R=c, G=kG, B=k4
//                  (0,1) G@R-row: G=c, R=k2, B=k3
//                  (1,0) G@B-row: G=c, R=k3, B=k2
//                  (1,1) B site:  B=c, G=kG, R=k4

constexpr int Bn = 16, Hn = 1024, Wn = 1024;
constexpr int TR = 4;                // output rows per thread

typedef float vfloat4 __attribute__((ext_vector_type(4)));
typedef float vfloat2 __attribute__((ext_vector_type(2)));

__global__ __launch_bounds__(256, 4) void demosaic_v5(
    const float* __restrict__ src, float* __restrict__ out)
{
    const int t  = threadIdx.x;          // 0..255 -> cols 4t..4t+3 (full width)
    const int y0 = blockIdx.x * TR;      // even
    const int b  = blockIdx.y;

    const float* sb = src + (size_t)b * Hn * Wn;

    const bool tL = (t == 0);
    const bool tR = (t == 255);
    const int xc = 4 * t;
    const int xl = tL ? 0 : xc - 2;          // 8B-aligned; clamped, zeroed below
    const int xr = tR ? (Wn - 2) : (xc + 4); // 8B-aligned; clamped, zeroed below

    // ---- Phase 1: 24 exact-window loads (8 rows x {8B,16B,8B}), independent.
    vfloat2 Lq[8]; vfloat4 Cq[8]; vfloat2 Rq[8];
    #pragma unroll
    for (int r = 0; r < 8; ++r) {
        int gy = y0 - 2 + r;
        int gyc = gy < 0 ? 0 : (gy > Hn - 1 ? Hn - 1 : gy);   // address-safe
        const float* p = sb + (size_t)gyc * Wn;
        Cq[r] = *(const vfloat4*)(p + xc);
        Lq[r] = *(const vfloat2*)(p + xl);
        Rq[r] = *(const vfloat2*)(p + xr);
    }

    // ---- Phase 2a: lane-edge zeroing in place (only t==0 / t==255 lanes).
    #pragma unroll
    for (int r = 0; r < 8; ++r) {
        if (tL) Lq[r] = vfloat2{0.f, 0.f};
        if (tR) Rq[r] = vfloat2{0.f, 0.f};
    }
    // ---- Phase 2b: image top/bottom zeroing — block-uniform scalar branch,
    //      taken by 2 of 256 y-blocks only. In-place, no extra registers.
    if (y0 == 0) {
        #pragma unroll
        for (int r = 0; r < 2; ++r) {
            Lq[r] = vfloat2{0.f, 0.f};
            Cq[r] = vfloat4{0.f, 0.f, 0.f, 0.f};
            Rq[r] = vfloat2{0.f, 0.f};
        }
    }
    if (y0 == Hn - TR) {
        #pragma unroll
        for (int r = 6; r < 8; ++r) {
            Lq[r] = vfloat2{0.f, 0.f};
            Cq[r] = vfloat4{0.f, 0.f, 0.f, 0.f};
            Rq[r] = vfloat2{0.f, 0.f};
        }
    }

    // ---- Phase 2c: window as pure SSA renames (regalloc coalesces; Lq/Cq/Rq
    //      die here — peak live stays ~64 + addressing).
    float v[8][8];
    #pragma unroll
    for (int r = 0; r < 8; ++r) {
        v[r][0] = Lq[r].x; v[r][1] = Lq[r].y;
        v[r][2] = Cq[r].x; v[r][3] = Cq[r].y;
        v[r][4] = Cq[r].z; v[r][5] = Cq[r].w;
        v[r][6] = Rq[r].x; v[r][7] = Rq[r].y;
    }

    const size_t HW = (size_t)Hn * Wn;
    float* ob = out + (size_t)b * 3 * HW + (size_t)y0 * Wn + xc;

    // ---- Phase 3: compute 4 output rows, store each as 3x nontemporal float4.
    #pragma unroll
    for (int i = 0; i < TR; ++i) {
        const float* r0 = v[i + 0];
        const float* r1 = v[i + 1];
        const float* r2 = v[i + 2];
        const float* r3 = v[i + 3];
        const float* r4 = v[i + 4];

        float R[4], G[4], Bc[4];
        #pragma unroll
        for (int j = 0; j < 4; ++j) {
            const float c   = r2[j + 2];
            const float h1  = r2[j + 1] + r2[j + 3];
            const float v1  = r1[j + 2] + r3[j + 2];
            const float h2  = r2[j] + r2[j + 4];
            const float v2s = r0[j + 2] + r4[j + 2];
            const float ax2 = h2 + v2s;
            const float dg  = r1[j + 1] + r1[j + 3] + r3[j + 1] + r3[j + 3];

            const int py = i & 1;            // compile-time (y0 even)
            const int px = j & 1;            // compile-time
            if (px == 0 && py == 0) {        // R site
                R[j] = c;
                G[j] = 0.5f * c + 0.25f * (h1 + v1) - 0.125f * ax2;
                Bc[j] = 0.75f * c + 0.25f * dg - 0.1875f * ax2;
            } else if (px == 1 && py == 0) { // G on R row
                R[j] = 0.625f * c + 0.5f * h1 - 0.125f * h2 + 0.0625f * v2s - 0.125f * dg;
                G[j] = c;
                Bc[j] = 0.625f * c + 0.5f * v1 - 0.125f * v2s + 0.0625f * h2 - 0.125f * dg;
            } else if (px == 0 && py == 1) { // G on B row
                R[j] = 0.625f * c + 0.5f * v1 - 0.125f * v2s + 0.0625f * h2 - 0.125f * dg;
                G[j] = c;
                Bc[j] = 0.625f * c + 0.5f * h1 - 0.125f * h2 + 0.0625f * v2s - 0.125f * dg;
            } else {                         // B site
                R[j] = 0.75f * c + 0.25f * dg - 0.1875f * ax2;
                G[j] = 0.5f * c + 0.25f * (h1 + v1) - 0.125f * ax2;
                Bc[j] = c;
            }
        }

        vfloat4 r4v = {R[0], R[1], R[2], R[3]};
        vfloat4 g4v = {G[0], G[1], G[2], G[3]};
        vfloat4 b4v = {Bc[0], Bc[1], Bc[2], Bc[3]};
        float* o = ob + (size_t)i * Wn;
        __builtin_nontemporal_store(r4v, (vfloat4*)o);
        __builtin_nontemporal_store(g4v, (vfloat4*)(o + HW));
        __builtin_nontemporal_store(b4v, (vfloat4*)(o + 2 * HW));
    }
}

extern "C" void kernel_launch(void* const* d_in, const int* in_sizes, int n_in,
                              void* d_out, int out_size, void* d_ws, size_t ws_size,
                              hipStream_t stream) {
    const float* cfa = (const float*)d_in[0];
    float* out = (float*)d_out;

    dim3 grid(Hn / TR, Bn);              // 256 x 16 = 4096 blocks, 256 thr each
    demosaic_v5<<<grid, dim3(256), 0, stream>>>(cfa, out);
}